// Round 4
// baseline (868.565 us; speedup 1.0000x reference)
//
#include <hip/hip_runtime.h>
#include <hip/hip_fp16.h>

typedef _Float16 f16;
typedef _Float16 f16x8 __attribute__((ext_vector_type(8)));
typedef float    f32x2 __attribute__((ext_vector_type(2)));
typedef float    f32x4 __attribute__((ext_vector_type(4)));

#define T_STEPS 2048
#define BATCH   16
#define DIM     1024

// ---------------------------------------------------------------------------
// async global->LDS (16B per lane). LDS dest must be wave-uniform base;
// hardware adds lane*16. Global address is per-lane.
__device__ __forceinline__ void async16(void* lds, const void* g) {
  __builtin_amdgcn_global_load_lds(
      (const __attribute__((address_space(1))) void*)g,
      (__attribute__((address_space(3))) void*)lds, 16, 0, 0);
}

#define WAITV_(n) asm volatile("s_waitcnt vmcnt(" #n ")" ::: "memory")
#define WAITV(n) WAITV_(n)

// v = f16 (low/high half of packed u32) * 1.0 + h, at f32 precision.
__device__ __forceinline__ float fma_mix_lo(unsigned p, float one, float h) {
  float d;
  asm("v_fma_mix_f32 %0, %1, %2, %3 op_sel:[0,0,0] op_sel_hi:[1,0,0]"
      : "=v"(d) : "v"(p), "v"(one), "v"(h));
  return d;
}
__device__ __forceinline__ float fma_mix_hi(unsigned p, float one, float h) {
  float d;
  asm("v_fma_mix_f32 %0, %1, %2, %3 op_sel:[1,0,0] op_sel_hi:[1,0,0]"
      : "=v"(d) : "v"(p), "v"(one), "v"(h));
  return d;
}

// ---------------------------------------------------------------------------
// f32 -> f16 convert, 8 elems/thread
__global__ void cvt_kernel(const float* __restrict__ src, f16* __restrict__ dst,
                           int n8) {
  int i = blockIdx.x * 256 + threadIdx.x;
  if (i >= n8) return;
  const float4* s4 = reinterpret_cast<const float4*>(src);
  float4 a = s4[2 * i], b = s4[2 * i + 1];
  f16x8 o;
  o[0] = (f16)a.x; o[1] = (f16)a.y; o[2] = (f16)a.z; o[3] = (f16)a.w;
  o[4] = (f16)b.x; o[5] = (f16)b.y; o[6] = (f16)b.z; o[7] = (f16)b.w;
  *reinterpret_cast<f16x8*>(dst + (size_t)i * 8) = o;
}

// ---------------------------------------------------------------------------
// Dual GEMM (unchanged from R3): P[m,e] = (x@W^T + b) * sigmoid(x@Wg^T + bg)
__global__ __launch_bounds__(256, 2)
void dual_gemm(const f16* __restrict__ xh, const f16* __restrict__ wh,
               const f16* __restrict__ wgh, const float* __restrict__ bias,
               const float* __restrict__ biasg, f16* __restrict__ P) {
  __shared__ f16 As[128 * 32];
  __shared__ f16 Bs[128 * 32];
  __shared__ f16 Gs[128 * 32];

  const int tid = threadIdx.x;
  const int bid = blockIdx.x;
  const int swz = ((bid & 7) << 8) | (bid >> 3);
  const int m0 = (swz >> 3) * 128;
  const int e0 = (swz & 7) * 128;

  const int lane = tid & 63;
  const int wave = tid >> 6;
  const int wrow = (wave >> 1) * 64;
  const int wcol = (wave & 1) * 64;
  const int fr = lane & 15;
  const int fc = lane >> 4;

  f32x4 acc1[4][4], acc2[4][4];
#pragma unroll
  for (int i = 0; i < 4; ++i)
#pragma unroll
    for (int j = 0; j < 4; ++j) {
      acc1[i][j] = {0.f, 0.f, 0.f, 0.f};
      acc2[i][j] = {0.f, 0.f, 0.f, 0.f};
    }

  const int    srow  = tid >> 2;
  const size_t sbyte = (size_t)(tid & 3) * 16;
  const char* ga = (const char*)xh  + ((size_t)(m0 + srow)) * 2048 + sbyte;
  const char* gb = (const char*)wh  + ((size_t)(e0 + srow)) * 2048 + sbyte;
  const char* gg = (const char*)wgh + ((size_t)(e0 + srow)) * 2048 + sbyte;
  char* la = (char*)&As[0] + (size_t)wave * 1024;
  char* lb = (char*)&Bs[0] + (size_t)wave * 1024;
  char* lg = (char*)&Gs[0] + (size_t)wave * 1024;

  for (int kk = 0; kk < 1024; kk += 32) {
    const size_t ko = (size_t)kk * 2;
    async16(la,        ga + ko);
    async16(la + 4096, ga + ko + (size_t)64 * 2048);
    async16(lb,        gb + ko);
    async16(lb + 4096, gb + ko + (size_t)64 * 2048);
    async16(lg,        gg + ko);
    async16(lg + 4096, gg + ko + (size_t)64 * 2048);
    asm volatile("s_waitcnt vmcnt(0)" ::: "memory");
    __syncthreads();

    f16x8 af[4], bf[4], gf[4];
#pragma unroll
    for (int i = 0; i < 4; ++i) {
      af[i] = *reinterpret_cast<const f16x8*>(&As[(wrow + i * 16 + fr) * 32 + fc * 8]);
      bf[i] = *reinterpret_cast<const f16x8*>(&Bs[(wcol + i * 16 + fr) * 32 + fc * 8]);
      gf[i] = *reinterpret_cast<const f16x8*>(&Gs[(wcol + i * 16 + fr) * 32 + fc * 8]);
    }
#pragma unroll
    for (int mi = 0; mi < 4; ++mi)
#pragma unroll
      for (int ni = 0; ni < 4; ++ni) {
        acc1[mi][ni] = __builtin_amdgcn_mfma_f32_16x16x32_f16(af[mi], bf[ni], acc1[mi][ni], 0, 0, 0);
        acc2[mi][ni] = __builtin_amdgcn_mfma_f32_16x16x32_f16(af[mi], gf[ni], acc2[mi][ni], 0, 0, 0);
      }
    __syncthreads();
  }

#pragma unroll
  for (int ni = 0; ni < 4; ++ni) {
    const int e = e0 + wcol + ni * 16 + fr;
    const float bb  = bias[e];
    const float bbg = biasg[e];
#pragma unroll
    for (int mi = 0; mi < 4; ++mi) {
      const int mrow = m0 + wrow + mi * 16 + fc * 4;
#pragma unroll
      for (int j = 0; j < 4; ++j) {
        float z1 = acc1[mi][ni][j] + bb;
        float z2 = acc2[mi][ni][j] + bbg;
        float s  = 1.0f / (1.0f + __expf(-z2));
        P[(size_t)(mrow + j) * DIM + e] = (f16)(z1 * s);
      }
    }
  }
}

// ---------------------------------------------------------------------------
// DPP-based wave64 sum: after shr 1/2/4/8 + bcast15/31, lane 63 = total
template <int CTRL>
__device__ __forceinline__ float dpp_add(float x) {
  int m = __builtin_amdgcn_update_dpp(0, __float_as_int(x), CTRL, 0xf, 0xf, true);
  return x + __int_as_float(m);
}

// ---------------------------------------------------------------------------
// Sequential scan, one wave per batch row, ISSUE-OPTIMIZED:
//  - v_fma_mix_f32 folds f16->f32 convert into the gated-add (16 instrs)
//  - f32x2/f32x4 vector math -> v_pk_fma_f32 / v_pk_mul_f32
//  - main loop unrolled x8: all ring slot offsets are ds_read immediates
//  - incremental pointers (no per-step address recompute)
//  - exact counted vmcnt (2 loads + 4 stores = 6 FIFO entries per step)
// Element d = c*256 + lane*4 + j; h4[c][j] is that element.
__global__ __launch_bounds__(64)
void scan_kernel(const f16* __restrict__ P, const float* __restrict__ h0,
                 float* __restrict__ hout) {
  __shared__ f16 ring[8 * DIM];  // 8 slots x 2KB
  const int b = blockIdx.x;
  const int lane = threadIdx.x;

  char* ring_b = (char*)&ring[0];
  const uint2* ring2 = (const uint2*)&ring[0];

  f32x4 h4[4];
  {
    const f32x4* s = (const f32x4*)(h0 + (size_t)b * DIM);
    f32x4* d = (f32x4*)(hout + (size_t)b * DIM);  // h[0] = h0
#pragma unroll
    for (int c = 0; c < 4; ++c) {
      h4[c] = s[c * 64 + lane];
      d[c * 64 + lane] = h4[c];
    }
  }
  __builtin_amdgcn_sched_barrier(0);  // pin: [4L,4S] before ring fill

  const char* pBase = (const char*)P + (size_t)b * (DIM * 2);
#pragma unroll
  for (int s = 0; s < 7; ++s) {  // fill slots 0..6 (14 loads)
    const char* g = pBase + (size_t)s * 32768 + (size_t)lane * 16;
    async16(ring_b + s * 2048, g);
    async16(ring_b + s * 2048 + 1024, g + 1024);
  }
  const char* gpref = pBase + (size_t)7 * 32768 + (size_t)lane * 16;
  float* hlane = hout + (size_t)BATCH * DIM + (size_t)b * DIM + lane * 4;
  const float one = 1.0f;
  __builtin_amdgcn_sched_barrier(0);

  // FIFO: [4L(h0) 4S(h0) 14L(ring)] -> slot0 ready at vmcnt<=12
  WAITV(12);
  uint2 pA[4], pB[4];
#pragma unroll
  for (int c = 0; c < 4; ++c) pA[c] = ring2[c * 64 + lane];

#define SCAN_STEP(CUR, NXT, SLOT_N, PREF_SLOT, WN, DO_PREF)                   \
  {                                                                           \
    WAITV(WN); /* slot SLOT_N landed */                                       \
    _Pragma("unroll")                                                         \
    for (int c = 0; c < 4; ++c)                                               \
      NXT[c] = ring2[(SLOT_N) * 256 + c * 64 + lane];                         \
    if (DO_PREF) {                                                            \
      async16(ring_b + (PREF_SLOT) * 2048, gpref);                            \
      async16(ring_b + (PREF_SLOT) * 2048 + 1024, gpref + 1024);              \
      gpref += 32768;                                                         \
    }                                                                         \
    __builtin_amdgcn_sched_barrier(0);                                        \
    f32x4 v4[4];                                                              \
    _Pragma("unroll")                                                         \
    for (int c = 0; c < 4; ++c) {                                             \
      v4[c][0] = fma_mix_lo(CUR[c].x, one, h4[c][0]);                         \
      v4[c][1] = fma_mix_hi(CUR[c].x, one, h4[c][1]);                         \
      v4[c][2] = fma_mix_lo(CUR[c].y, one, h4[c][2]);                         \
      v4[c][3] = fma_mix_hi(CUR[c].y, one, h4[c][3]);                         \
    }                                                                         \
    f32x2 sE, sO;                                                             \
    {                                                                         \
      f32x2 e0v = __builtin_shufflevector(v4[0], v4[0], 0, 1);                \
      f32x2 o0v = __builtin_shufflevector(v4[0], v4[0], 2, 3);                \
      sE = e0v * e0v;                                                         \
      sO = o0v * o0v;                                                         \
      _Pragma("unroll")                                                       \
      for (int c = 1; c < 4; ++c) {                                           \
        f32x2 ec = __builtin_shufflevector(v4[c], v4[c], 0, 1);               \
        f32x2 oc = __builtin_shufflevector(v4[c], v4[c], 2, 3);               \
        sE += ec * ec;                                                        \
        sO += oc * oc;                                                        \
      }                                                                       \
    }                                                                         \
    f32x2 sC = sE + sO;                                                       \
    float ss = sC[0] + sC[1];                                                 \
    ss = dpp_add<0x111>(ss);                                                  \
    ss = dpp_add<0x112>(ss);                                                  \
    ss = dpp_add<0x114>(ss);                                                  \
    ss = dpp_add<0x118>(ss);                                                  \
    ss = dpp_add<0x142>(ss);                                                  \
    ss = dpp_add<0x143>(ss);                                                  \
    float tot = __int_as_float(__builtin_amdgcn_readlane(__float_as_int(ss), 63)); \
    float r = __builtin_amdgcn_rsqf(fmaf(tot, 9.765625e-4f, 1e-6f));          \
    _Pragma("unroll")                                                         \
    for (int c = 0; c < 4; ++c) h4[c] = v4[c] * r;                            \
    _Pragma("unroll")                                                         \
    for (int c = 0; c < 4; ++c) *(f32x4*)(hlane + c * 256) = h4[c];           \
    hlane += BATCH * DIM;                                                     \
  }

  // warmup t=0..5: slot t+1 from prologue; exact WN = 10+4t
  SCAN_STEP(pA, pB, 1, 7, 10, 1);
  SCAN_STEP(pB, pA, 2, 0, 14, 1);
  SCAN_STEP(pA, pB, 3, 1, 18, 1);
  SCAN_STEP(pB, pA, 4, 2, 22, 1);
  SCAN_STEP(pA, pB, 5, 3, 26, 1);
  SCAN_STEP(pB, pA, 6, 4, 30, 1);

  // steady: t=6..2037 (254 x 8 steps). Slot t+1 issued at t-6:
  // after its 2 loads: 4S + 5*6 = 34 outstanding -> vmcnt(34)
#pragma unroll 1
  for (int k = 0; k < 254; ++k) {
    SCAN_STEP(pA, pB, 7, 5, 34, 1);
    SCAN_STEP(pB, pA, 0, 6, 34, 1);
    SCAN_STEP(pA, pB, 1, 7, 34, 1);
    SCAN_STEP(pB, pA, 2, 0, 34, 1);
    SCAN_STEP(pA, pB, 3, 1, 34, 1);
    SCAN_STEP(pB, pA, 4, 2, 34, 1);
    SCAN_STEP(pA, pB, 5, 3, 34, 1);
    SCAN_STEP(pB, pA, 6, 4, 34, 1);
  }
  // t=2038..2040 (still prefetch rows 2045..2047)
  SCAN_STEP(pA, pB, 7, 5, 34, 1);
  SCAN_STEP(pB, pA, 0, 6, 34, 1);
  SCAN_STEP(pA, pB, 1, 7, 34, 1);
  // tail t=2041..2047, no prefetch (4S/step); exact counted drains
  SCAN_STEP(pB, pA, 2, 0, 34, 0);
  SCAN_STEP(pA, pB, 3, 1, 32, 0);
  SCAN_STEP(pB, pA, 4, 2, 30, 0);
  SCAN_STEP(pA, pB, 5, 3, 28, 0);
  SCAN_STEP(pB, pA, 6, 4, 26, 0);
  SCAN_STEP(pA, pB, 7, 5, 24, 0);
  SCAN_STEP(pB, pA, 0, 6, 22, 0);  // reads stale slot 0, never consumed
#undef SCAN_STEP
}

// ---------------------------------------------------------------------------
// out = h * silu(h) = h^2 * sigmoid(h), elementwise over hs (h rows 1..T)
__global__ void silu_out_kernel(const float* __restrict__ hsrc,
                                float* __restrict__ out, int n4) {
  int stride = gridDim.x * blockDim.x;
  for (int i = blockIdx.x * blockDim.x + threadIdx.x; i < n4; i += stride) {
    float4 v = reinterpret_cast<const float4*>(hsrc)[i];
    float4 o;
    o.x = v.x * v.x / (1.0f + __expf(-v.x));
    o.y = v.y * v.y / (1.0f + __expf(-v.y));
    o.z = v.z * v.z / (1.0f + __expf(-v.z));
    o.w = v.w * v.w / (1.0f + __expf(-v.w));
    reinterpret_cast<float4*>(out)[i] = o;
  }
}

// ---------------------------------------------------------------------------
extern "C" void kernel_launch(void* const* d_in, const int* in_sizes, int n_in,
                              void* d_out, int out_size, void* d_ws, size_t ws_size,
                              hipStream_t stream) {
  const float* x  = (const float*)d_in[0];  // [T,B,D]
  const float* h0 = (const float*)d_in[1];  // [B,D]
  const float* W  = (const float*)d_in[2];  // [D,D]
  const float* Wg = (const float*)d_in[3];  // [D,D]
  const float* bb = (const float*)d_in[4];  // [D]
  const float* bg = (const float*)d_in[5];  // [D]

  float* out  = (float*)d_out;                              // [T,B,D]
  float* hout = out + (size_t)T_STEPS * BATCH * DIM;        // [T+1,B,D]

  char* ws = (char*)d_ws;
  f16* xh  = (f16*)(ws);                                    // 64 MiB
  f16* wh  = (f16*)(ws + (size_t)67108864);                 // 2 MiB
  f16* wgh = (f16*)(ws + (size_t)69206016);                 // 2 MiB
  f16* P   = (f16*)(ws + (size_t)71303168);                 // 64 MiB

  cvt_kernel<<<16384, 256, 0, stream>>>(x,  xh,  4194304);
  cvt_kernel<<<512,   256, 0, stream>>>(W,  wh,  131072);
  cvt_kernel<<<512,   256, 0, stream>>>(Wg, wgh, 131072);

  dual_gemm<<<2048, 256, 0, stream>>>(xh, wh, wgh, bb, bg, P);

  scan_kernel<<<BATCH, 64, 0, stream>>>(P, h0, hout);

  silu_out_kernel<<<2048, 256, 0, stream>>>(hout + BATCH * DIM, out, 8388608);
}

// Round 5
// 859.031 us; speedup vs baseline: 1.0111x; 1.0111x over previous
//
#include <hip/hip_runtime.h>
#include <hip/hip_fp16.h>

typedef _Float16 f16;
typedef _Float16 f16x8 __attribute__((ext_vector_type(8)));
typedef float    f32x2 __attribute__((ext_vector_type(2)));
typedef float    f32x4 __attribute__((ext_vector_type(4)));

#define T_STEPS 2048
#define BATCH   16
#define DIM     1024

// ---------------------------------------------------------------------------
// async global->LDS (16B per lane). LDS dest must be wave-uniform base;
// hardware adds lane*16. Global address is per-lane.
__device__ __forceinline__ void async16(void* lds, const void* g) {
  __builtin_amdgcn_global_load_lds(
      (const __attribute__((address_space(1))) void*)g,
      (__attribute__((address_space(3))) void*)lds, 16, 0, 0);
}

#define WAITV_(n) asm volatile("s_waitcnt vmcnt(" #n ")" ::: "memory")
#define WAITV(n) WAITV_(n)

// v = f16 (low/high half of packed u32) * 1.0 + h, at f32 precision.
__device__ __forceinline__ float fma_mix_lo(unsigned p, float one, float h) {
  float d;
  asm("v_fma_mix_f32 %0, %1, %2, %3 op_sel:[0,0,0] op_sel_hi:[1,0,0]"
      : "=v"(d) : "v"(p), "v"(one), "v"(h));
  return d;
}
__device__ __forceinline__ float fma_mix_hi(unsigned p, float one, float h) {
  float d;
  asm("v_fma_mix_f32 %0, %1, %2, %3 op_sel:[1,0,0] op_sel_hi:[1,0,0]"
      : "=v"(d) : "v"(p), "v"(one), "v"(h));
  return d;
}

// ---------------------------------------------------------------------------
// f32 -> f16 convert, 8 elems/thread
__global__ void cvt_kernel(const float* __restrict__ src, f16* __restrict__ dst,
                           int n8) {
  int i = blockIdx.x * 256 + threadIdx.x;
  if (i >= n8) return;
  const float4* s4 = reinterpret_cast<const float4*>(src);
  float4 a = s4[2 * i], b = s4[2 * i + 1];
  f16x8 o;
  o[0] = (f16)a.x; o[1] = (f16)a.y; o[2] = (f16)a.z; o[3] = (f16)a.w;
  o[4] = (f16)b.x; o[5] = (f16)b.y; o[6] = (f16)b.z; o[7] = (f16)b.w;
  *reinterpret_cast<f16x8*>(dst + (size_t)i * 8) = o;
}

// ---------------------------------------------------------------------------
// Dual GEMM (unchanged from R3): P[m,e] = (x@W^T + b) * sigmoid(x@Wg^T + bg)
__global__ __launch_bounds__(256, 2)
void dual_gemm(const f16* __restrict__ xh, const f16* __restrict__ wh,
               const f16* __restrict__ wgh, const float* __restrict__ bias,
               const float* __restrict__ biasg, f16* __restrict__ P) {
  __shared__ f16 As[128 * 32];
  __shared__ f16 Bs[128 * 32];
  __shared__ f16 Gs[128 * 32];

  const int tid = threadIdx.x;
  const int bid = blockIdx.x;
  const int swz = ((bid & 7) << 8) | (bid >> 3);
  const int m0 = (swz >> 3) * 128;
  const int e0 = (swz & 7) * 128;

  const int lane = tid & 63;
  const int wave = tid >> 6;
  const int wrow = (wave >> 1) * 64;
  const int wcol = (wave & 1) * 64;
  const int fr = lane & 15;
  const int fc = lane >> 4;

  f32x4 acc1[4][4], acc2[4][4];
#pragma unroll
  for (int i = 0; i < 4; ++i)
#pragma unroll
    for (int j = 0; j < 4; ++j) {
      acc1[i][j] = {0.f, 0.f, 0.f, 0.f};
      acc2[i][j] = {0.f, 0.f, 0.f, 0.f};
    }

  const int    srow  = tid >> 2;
  const size_t sbyte = (size_t)(tid & 3) * 16;
  const char* ga = (const char*)xh  + ((size_t)(m0 + srow)) * 2048 + sbyte;
  const char* gb = (const char*)wh  + ((size_t)(e0 + srow)) * 2048 + sbyte;
  const char* gg = (const char*)wgh + ((size_t)(e0 + srow)) * 2048 + sbyte;
  char* la = (char*)&As[0] + (size_t)wave * 1024;
  char* lb = (char*)&Bs[0] + (size_t)wave * 1024;
  char* lg = (char*)&Gs[0] + (size_t)wave * 1024;

  for (int kk = 0; kk < 1024; kk += 32) {
    const size_t ko = (size_t)kk * 2;
    async16(la,        ga + ko);
    async16(la + 4096, ga + ko + (size_t)64 * 2048);
    async16(lb,        gb + ko);
    async16(lb + 4096, gb + ko + (size_t)64 * 2048);
    async16(lg,        gg + ko);
    async16(lg + 4096, gg + ko + (size_t)64 * 2048);
    asm volatile("s_waitcnt vmcnt(0)" ::: "memory");
    __syncthreads();

    f16x8 af[4], bf[4], gf[4];
#pragma unroll
    for (int i = 0; i < 4; ++i) {
      af[i] = *reinterpret_cast<const f16x8*>(&As[(wrow + i * 16 + fr) * 32 + fc * 8]);
      bf[i] = *reinterpret_cast<const f16x8*>(&Bs[(wcol + i * 16 + fr) * 32 + fc * 8]);
      gf[i] = *reinterpret_cast<const f16x8*>(&Gs[(wcol + i * 16 + fr) * 32 + fc * 8]);
    }
#pragma unroll
    for (int mi = 0; mi < 4; ++mi)
#pragma unroll
      for (int ni = 0; ni < 4; ++ni) {
        acc1[mi][ni] = __builtin_amdgcn_mfma_f32_16x16x32_f16(af[mi], bf[ni], acc1[mi][ni], 0, 0, 0);
        acc2[mi][ni] = __builtin_amdgcn_mfma_f32_16x16x32_f16(af[mi], gf[ni], acc2[mi][ni], 0, 0, 0);
      }
    __syncthreads();
  }

#pragma unroll
  for (int ni = 0; ni < 4; ++ni) {
    const int e = e0 + wcol + ni * 16 + fr;
    const float bb  = bias[e];
    const float bbg = biasg[e];
#pragma unroll
    for (int mi = 0; mi < 4; ++mi) {
      const int mrow = m0 + wrow + mi * 16 + fc * 4;
#pragma unroll
      for (int j = 0; j < 4; ++j) {
        float z1 = acc1[mi][ni][j] + bb;
        float z2 = acc2[mi][ni][j] + bbg;
        float s  = 1.0f / (1.0f + __expf(-z2));
        P[(size_t)(mrow + j) * DIM + e] = (f16)(z1 * s);
      }
    }
  }
}

// ---------------------------------------------------------------------------
// DPP-based wave64 sum: after shr 1/2/4/8 + bcast15/31, lane 63 = total
template <int CTRL>
__device__ __forceinline__ float dpp_add(float x) {
  int m = __builtin_amdgcn_update_dpp(0, __float_as_int(x), CTRL, 0xf, 0xf, true);
  return x + __int_as_float(m);
}

// ---------------------------------------------------------------------------
// Sequential scan, one wave per batch row, ISSUE-OPTIMIZED:
//  - v_fma_mix_f32 folds f16->f32 convert into the gated-add (16 instrs)
//  - f32x2/f32x4 vector math -> v_pk_fma_f32 / v_pk_mul_f32
//  - main loop unrolled x8: all ring slot offsets are ds_read immediates
//  - incremental pointers (no per-step address recompute)
//  - exact counted vmcnt (2 loads + 4 stores = 6 FIFO entries per step)
// Element d = c*256 + lane*4 + j; h4[c][j] is that element.
__global__ __launch_bounds__(64)
void scan_kernel(const f16* __restrict__ P, const float* __restrict__ h0,
                 float* __restrict__ hout) {
  __shared__ f16 ring[8 * DIM];  // 8 slots x 2KB
  const int b = blockIdx.x;
  const int lane = threadIdx.x;

  char* ring_b = (char*)&ring[0];
  const uint2* ring2 = (const uint2*)&ring[0];

  f32x4 h4[4];
  {
    const f32x4* s = (const f32x4*)(h0 + (size_t)b * DIM);
    f32x4* d = (f32x4*)(hout + (size_t)b * DIM);  // h[0] = h0
#pragma unroll
    for (int c = 0; c < 4; ++c) {
      h4[c] = s[c * 64 + lane];
      d[c * 64 + lane] = h4[c];
    }
  }
  __builtin_amdgcn_sched_barrier(0);  // pin: [4L,4S] before ring fill

  const char* pBase = (const char*)P + (size_t)b * (DIM * 2);
#pragma unroll
  for (int s = 0; s < 7; ++s) {  // fill slots 0..6 (14 loads)
    const char* g = pBase + (size_t)s * 32768 + (size_t)lane * 16;
    async16(ring_b + s * 2048, g);
    async16(ring_b + s * 2048 + 1024, g + 1024);
  }
  const char* gpref = pBase + (size_t)7 * 32768 + (size_t)lane * 16;
  float* hlane = hout + (size_t)BATCH * DIM + (size_t)b * DIM + lane * 4;
  const float one = 1.0f;
  __builtin_amdgcn_sched_barrier(0);

  // FIFO: [4L(h0) 4S(h0) 14L(ring)] -> slot0 ready at vmcnt<=12
  WAITV(12);
  uint2 pA[4], pB[4];
#pragma unroll
  for (int c = 0; c < 4; ++c) pA[c] = ring2[c * 64 + lane];

#define SCAN_STEP(CUR, NXT, SLOT_N, PREF_SLOT, WN, DO_PREF)                   \
  {                                                                           \
    WAITV(WN); /* slot SLOT_N landed */                                       \
    _Pragma("unroll")                                                         \
    for (int c = 0; c < 4; ++c)                                               \
      NXT[c] = ring2[(SLOT_N) * 256 + c * 64 + lane];                         \
    if (DO_PREF) {                                                            \
      async16(ring_b + (PREF_SLOT) * 2048, gpref);                            \
      async16(ring_b + (PREF_SLOT) * 2048 + 1024, gpref + 1024);              \
      gpref += 32768;                                                         \
    }                                                                         \
    __builtin_amdgcn_sched_barrier(0);                                        \
    f32x4 v4[4];                                                              \
    _Pragma("unroll")                                                         \
    for (int c = 0; c < 4; ++c) {                                             \
      v4[c][0] = fma_mix_lo(CUR[c].x, one, h4[c][0]);                         \
      v4[c][1] = fma_mix_hi(CUR[c].x, one, h4[c][1]);                         \
      v4[c][2] = fma_mix_lo(CUR[c].y, one, h4[c][2]);                         \
      v4[c][3] = fma_mix_hi(CUR[c].y, one, h4[c][3]);                         \
    }                                                                         \
    f32x2 sE, sO;                                                             \
    {                                                                         \
      f32x2 e0v = __builtin_shufflevector(v4[0], v4[0], 0, 1);                \
      f32x2 o0v = __builtin_shufflevector(v4[0], v4[0], 2, 3);                \
      sE = e0v * e0v;                                                         \
      sO = o0v * o0v;                                                         \
      _Pragma("unroll")                                                       \
      for (int c = 1; c < 4; ++c) {                                           \
        f32x2 ec = __builtin_shufflevector(v4[c], v4[c], 0, 1);               \
        f32x2 oc = __builtin_shufflevector(v4[c], v4[c], 2, 3);               \
        sE += ec * ec;                                                        \
        sO += oc * oc;                                                        \
      }                                                                       \
    }                                                                         \
    f32x2 sC = sE + sO;                                                       \
    float ss = sC[0] + sC[1];                                                 \
    ss = dpp_add<0x111>(ss);                                                  \
    ss = dpp_add<0x112>(ss);                                                  \
    ss = dpp_add<0x114>(ss);                                                  \
    ss = dpp_add<0x118>(ss);                                                  \
    ss = dpp_add<0x142>(ss);                                                  \
    ss = dpp_add<0x143>(ss);                                                  \
    float tot = __int_as_float(__builtin_amdgcn_readlane(__float_as_int(ss), 63)); \
    float r = __builtin_amdgcn_rsqf(fmaf(tot, 9.765625e-4f, 1e-6f));          \
    _Pragma("unroll")                                                         \
    for (int c = 0; c < 4; ++c) h4[c] = v4[c] * r;                            \
    _Pragma("unroll")                                                         \
    for (int c = 0; c < 4; ++c) *(f32x4*)(hlane + c * 256) = h4[c];           \
    hlane += BATCH * DIM;                                                     \
  }

  // warmup t=0..5: slot t+1 from prologue; exact WN = 10+4t
  SCAN_STEP(pA, pB, 1, 7, 10, 1);
  SCAN_STEP(pB, pA, 2, 0, 14, 1);
  SCAN_STEP(pA, pB, 3, 1, 18, 1);
  SCAN_STEP(pB, pA, 4, 2, 22, 1);
  SCAN_STEP(pA, pB, 5, 3, 26, 1);
  SCAN_STEP(pB, pA, 6, 4, 30, 1);

  // steady: t=6..2037 (254 x 8 steps). Slot t+1 issued at t-6:
  // after its 2 loads: 4S + 5*6 = 34 outstanding -> vmcnt(34)
#pragma unroll 1
  for (int k = 0; k < 254; ++k) {
    SCAN_STEP(pA, pB, 7, 5, 34, 1);
    SCAN_STEP(pB, pA, 0, 6, 34, 1);
    SCAN_STEP(pA, pB, 1, 7, 34, 1);
    SCAN_STEP(pB, pA, 2, 0, 34, 1);
    SCAN_STEP(pA, pB, 3, 1, 34, 1);
    SCAN_STEP(pB, pA, 4, 2, 34, 1);
    SCAN_STEP(pA, pB, 5, 3, 34, 1);
    SCAN_STEP(pB, pA, 6, 4, 34, 1);
  }
  // t=2038..2040 (still prefetch rows 2045..2047)
  SCAN_STEP(pA, pB, 7, 5, 34, 1);
  SCAN_STEP(pB, pA, 0, 6, 34, 1);
  SCAN_STEP(pA, pB, 1, 7, 34, 1);
  // tail t=2041..2047, no prefetch (4S/step); exact counted drains
  SCAN_STEP(pB, pA, 2, 0, 34, 0);
  SCAN_STEP(pA, pB, 3, 1, 32, 0);
  SCAN_STEP(pB, pA, 4, 2, 30, 0);
  SCAN_STEP(pA, pB, 5, 3, 28, 0);
  SCAN_STEP(pB, pA, 6, 4, 26, 0);
  SCAN_STEP(pA, pB, 7, 5, 24, 0);
  SCAN_STEP(pB, pA, 0, 6, 22, 0);  // reads stale slot 0, never consumed
#undef SCAN_STEP
}

// ---------------------------------------------------------------------------
// out = h * silu(h) = h^2 * sigmoid(h), elementwise over hs (h rows 1..T)
__global__ void silu_out_kernel(const float* __restrict__ hsrc,
                                float* __restrict__ out, int n4) {
  int stride = gridDim.x * blockDim.x;
  for (int i = blockIdx.x * blockDim.x + threadIdx.x; i < n4; i += stride) {
    float4 v = reinterpret_cast<const float4*>(hsrc)[i];
    float4 o;
    o.x = v.x * v.x / (1.0f + __expf(-v.x));
    o.y = v.y * v.y / (1.0f + __expf(-v.y));
    o.z = v.z * v.z / (1.0f + __expf(-v.z));
    o.w = v.w * v.w / (1.0f + __expf(-v.w));
    reinterpret_cast<float4*>(out)[i] = o;
  }
}

// ---------------------------------------------------------------------------
extern "C" void kernel_launch(void* const* d_in, const int* in_sizes, int n_in,
                              void* d_out, int out_size, void* d_ws, size_t ws_size,
                              hipStream_t stream) {
  const float* x  = (const float*)d_in[0];  // [T,B,D]
  const float* h0 = (const float*)d_in[1];  // [B,D]
  const float* W  = (const float*)d_in[2];  // [D,D]
  const float* Wg = (const float*)d_in[3];  // [D,D]
  const float* bb = (const float*)d_in[4];  // [D]
  const float* bg = (const float*)d_in[5];  // [D]

  float* out  = (float*)d_out;                              // [T,B,D]
  float* hout = out + (size_t)T_STEPS * BATCH * DIM;        // [T+1,B,D]

  char* ws = (char*)d_ws;
  f16* xh  = (f16*)(ws);                                    // 64 MiB
  f16* wh  = (f16*)(ws + (size_t)67108864);                 // 2 MiB
  f16* wgh = (f16*)(ws + (size_t)69206016);                 // 2 MiB
  f16* P   = (f16*)(ws + (size_t)71303168);                 // 64 MiB

  cvt_kernel<<<16384, 256, 0, stream>>>(x,  xh,  4194304);
  cvt_kernel<<<512,   256, 0, stream>>>(W,  wh,  131072);
  cvt_kernel<<<512,   256, 0, stream>>>(Wg, wgh, 131072);

  dual_gemm<<<2048, 256, 0, stream>>>(xh, wh, wgh, bb, bg, P);

  scan_kernel<<<BATCH, 64, 0, stream>>>(P, h0, hout);

  silu_out_kernel<<<2048, 256, 0, stream>>>(hout + BATCH * DIM, out, 8388608);
}

// Round 6
// 549.643 us; speedup vs baseline: 1.5802x; 1.5629x over previous
//
#include <hip/hip_runtime.h>
#include <hip/hip_fp16.h>

typedef _Float16 f16;
typedef _Float16 f16x8 __attribute__((ext_vector_type(8)));
typedef float    f32x2 __attribute__((ext_vector_type(2)));
typedef float    f32x4 __attribute__((ext_vector_type(4)));
typedef unsigned ui4   __attribute__((ext_vector_type(4)));

#define T_STEPS 2048
#define BATCH   16
#define DIM     1024

// ---------------------------------------------------------------------------
// async global->LDS (16B per lane), used only by the GEMM.
__device__ __forceinline__ void async16(void* lds, const void* g) {
  __builtin_amdgcn_global_load_lds(
      (const __attribute__((address_space(1))) void*)g,
      (__attribute__((address_space(3))) void*)lds, 16, 0, 0);
}

// v = f16 (low/high half of packed u32) * 1.0 + h, at f32 precision.
__device__ __forceinline__ float fma_mix_lo(unsigned p, float one, float h) {
  float d;
  asm("v_fma_mix_f32 %0, %1, %2, %3 op_sel:[0,0,0] op_sel_hi:[1,0,0]"
      : "=v"(d) : "v"(p), "v"(one), "v"(h));
  return d;
}
__device__ __forceinline__ float fma_mix_hi(unsigned p, float one, float h) {
  float d;
  asm("v_fma_mix_f32 %0, %1, %2, %3 op_sel:[1,0,0] op_sel_hi:[1,0,0]"
      : "=v"(d) : "v"(p), "v"(one), "v"(h));
  return d;
}

// ---------------------------------------------------------------------------
// f32 -> f16 convert, 8 elems/thread
__global__ void cvt_kernel(const float* __restrict__ src, f16* __restrict__ dst,
                           int n8) {
  int i = blockIdx.x * 256 + threadIdx.x;
  if (i >= n8) return;
  const float4* s4 = reinterpret_cast<const float4*>(src);
  float4 a = s4[2 * i], b = s4[2 * i + 1];
  f16x8 o;
  o[0] = (f16)a.x; o[1] = (f16)a.y; o[2] = (f16)a.z; o[3] = (f16)a.w;
  o[4] = (f16)b.x; o[5] = (f16)b.y; o[6] = (f16)b.z; o[7] = (f16)b.w;
  *reinterpret_cast<f16x8*>(dst + (size_t)i * 8) = o;
}

// ---------------------------------------------------------------------------
// Dual GEMM (unchanged): P[m,e] = (x@W^T + b) * sigmoid(x@Wg^T + bg), f16 out
__global__ __launch_bounds__(256, 2)
void dual_gemm(const f16* __restrict__ xh, const f16* __restrict__ wh,
               const f16* __restrict__ wgh, const float* __restrict__ bias,
               const float* __restrict__ biasg, f16* __restrict__ P) {
  __shared__ f16 As[128 * 32];
  __shared__ f16 Bs[128 * 32];
  __shared__ f16 Gs[128 * 32];

  const int tid = threadIdx.x;
  const int bid = blockIdx.x;
  const int swz = ((bid & 7) << 8) | (bid >> 3);
  const int m0 = (swz >> 3) * 128;
  const int e0 = (swz & 7) * 128;

  const int lane = tid & 63;
  const int wave = tid >> 6;
  const int wrow = (wave >> 1) * 64;
  const int wcol = (wave & 1) * 64;
  const int fr = lane & 15;
  const int fc = lane >> 4;

  f32x4 acc1[4][4], acc2[4][4];
#pragma unroll
  for (int i = 0; i < 4; ++i)
#pragma unroll
    for (int j = 0; j < 4; ++j) {
      acc1[i][j] = {0.f, 0.f, 0.f, 0.f};
      acc2[i][j] = {0.f, 0.f, 0.f, 0.f};
    }

  const int    srow  = tid >> 2;
  const size_t sbyte = (size_t)(tid & 3) * 16;
  const char* ga = (const char*)xh  + ((size_t)(m0 + srow)) * 2048 + sbyte;
  const char* gb = (const char*)wh  + ((size_t)(e0 + srow)) * 2048 + sbyte;
  const char* gg = (const char*)wgh + ((size_t)(e0 + srow)) * 2048 + sbyte;
  char* la = (char*)&As[0] + (size_t)wave * 1024;
  char* lb = (char*)&Bs[0] + (size_t)wave * 1024;
  char* lg = (char*)&Gs[0] + (size_t)wave * 1024;

  for (int kk = 0; kk < 1024; kk += 32) {
    const size_t ko = (size_t)kk * 2;
    async16(la,        ga + ko);
    async16(la + 4096, ga + ko + (size_t)64 * 2048);
    async16(lb,        gb + ko);
    async16(lb + 4096, gb + ko + (size_t)64 * 2048);
    async16(lg,        gg + ko);
    async16(lg + 4096, gg + ko + (size_t)64 * 2048);
    asm volatile("s_waitcnt vmcnt(0)" ::: "memory");
    __syncthreads();

    f16x8 af[4], bf[4], gf[4];
#pragma unroll
    for (int i = 0; i < 4; ++i) {
      af[i] = *reinterpret_cast<const f16x8*>(&As[(wrow + i * 16 + fr) * 32 + fc * 8]);
      bf[i] = *reinterpret_cast<const f16x8*>(&Bs[(wcol + i * 16 + fr) * 32 + fc * 8]);
      gf[i] = *reinterpret_cast<const f16x8*>(&Gs[(wcol + i * 16 + fr) * 32 + fc * 8]);
    }
#pragma unroll
    for (int mi = 0; mi < 4; ++mi)
#pragma unroll
      for (int ni = 0; ni < 4; ++ni) {
        acc1[mi][ni] = __builtin_amdgcn_mfma_f32_16x16x32_f16(af[mi], bf[ni], acc1[mi][ni], 0, 0, 0);
        acc2[mi][ni] = __builtin_amdgcn_mfma_f32_16x16x32_f16(af[mi], gf[ni], acc2[mi][ni], 0, 0, 0);
      }
    __syncthreads();
  }

#pragma unroll
  for (int ni = 0; ni < 4; ++ni) {
    const int e = e0 + wcol + ni * 16 + fr;
    const float bb  = bias[e];
    const float bbg = biasg[e];
#pragma unroll
    for (int mi = 0; mi < 4; ++mi) {
      const int mrow = m0 + wrow + mi * 16 + fc * 4;
#pragma unroll
      for (int j = 0; j < 4; ++j) {
        float z1 = acc1[mi][ni][j] + bb;
        float z2 = acc2[mi][ni][j] + bbg;
        float s  = 1.0f / (1.0f + __expf(-z2));
        P[(size_t)(mrow + j) * DIM + e] = (f16)(z1 * s);
      }
    }
  }
}

// ---------------------------------------------------------------------------
// DPP-based wave64 sum: after shr 1/2/4/8 + bcast15/31, lane 63 = total
template <int CTRL>
__device__ __forceinline__ float dpp_add(float x) {
  int m = __builtin_amdgcn_update_dpp(0, __float_as_int(x), CTRL, 0xf, 0xf, true);
  return x + __int_as_float(m);
}

// ---------------------------------------------------------------------------
// Sequential scan, one wave per batch row.
//  - __launch_bounds__(64, 1): VGPR budget ~512 so the depth-8 register
//    prefetch ring (pf[8][2] = 64 VGPRs) is NOT sunk by the allocator
//    (R2's collapse: default occupancy target forced <=64 VGPRs total).
//  - NO asm waits / sched_barriers: compiler schedules across steps (R2-best).
//  - v_fma_mix folds f16->f32 convert into the gated add; packed f32x2
//    square-accumulate; dwordx4 loads (2/step) and stores (4/step).
// Element mapping: lane l holds f32/f16 elements [8l..8l+7] (chunks 0,1) and
// [512+8l..512+8l+7] (chunks 2,3).
__global__ __launch_bounds__(64, 1)
void scan_kernel(const f16* __restrict__ P, const float* __restrict__ h0,
                 float* __restrict__ hout) {
  const int b = blockIdx.x;
  const int lane = threadIdx.x;

  f32x4 h4[4];
  {
    const f32x4* s = (const f32x4*)(h0 + (size_t)b * DIM);
    f32x4* d = (f32x4*)(hout + (size_t)b * DIM);  // h[0] = h0
    h4[0] = s[2 * lane];       d[2 * lane]       = h4[0];
    h4[1] = s[2 * lane + 1];   d[2 * lane + 1]   = h4[1];
    h4[2] = s[128 + 2 * lane]; d[128 + 2 * lane] = h4[2];
    h4[3] = s[129 + 2 * lane]; d[129 + 2 * lane] = h4[3];
  }

  // depth-8 register ring: pf[u][0] = elements 8l..8l+7 (ui4 = 4x packed f16
  // pairs), pf[u][1] = elements 512+8l..512+8l+7.
  ui4 pf[8][2];
#pragma unroll
  for (int u = 0; u < 8; ++u) {
    const ui4* pr = (const ui4*)(P + ((size_t)u * BATCH + b) * DIM);
    pf[u][0] = pr[lane];
    pf[u][1] = pr[64 + lane];
  }

  const float one = 1.0f;

  for (int t0 = 0; t0 < T_STEPS; t0 += 8) {
#pragma unroll
    for (int u = 0; u < 8; ++u) {
      const int t = t0 + u;

      // consume slot u
      f32x4 v4[4];
#pragma unroll
      for (int c = 0; c < 4; ++c) {
        const unsigned w0 = pf[u][c >> 1][(c & 1) * 2];
        const unsigned w1 = pf[u][c >> 1][(c & 1) * 2 + 1];
        v4[c][0] = fma_mix_lo(w0, one, h4[c][0]);
        v4[c][1] = fma_mix_hi(w0, one, h4[c][1]);
        v4[c][2] = fma_mix_lo(w1, one, h4[c][2]);
        v4[c][3] = fma_mix_hi(w1, one, h4[c][3]);
      }

      // reissue prefetch into slot u, branch-free (wrap keeps address valid;
      // wrapped rows load but are never consumed)
      {
        const int tp = (t + 8) & (T_STEPS - 1);
        const ui4* pr = (const ui4*)(P + ((size_t)tp * BATCH + b) * DIM);
        pf[u][0] = pr[lane];
        pf[u][1] = pr[64 + lane];
      }

      // sum of squares (packed f32x2 ops)
      f32x2 sE, sO;
      {
        f32x2 e0v = __builtin_shufflevector(v4[0], v4[0], 0, 1);
        f32x2 o0v = __builtin_shufflevector(v4[0], v4[0], 2, 3);
        sE = e0v * e0v;
        sO = o0v * o0v;
#pragma unroll
        for (int c = 1; c < 4; ++c) {
          f32x2 ec = __builtin_shufflevector(v4[c], v4[c], 0, 1);
          f32x2 oc = __builtin_shufflevector(v4[c], v4[c], 2, 3);
          sE += ec * ec;
          sO += oc * oc;
        }
      }
      f32x2 sC = sE + sO;
      float ss = sC[0] + sC[1];
      ss = dpp_add<0x111>(ss);  // row_shr:1
      ss = dpp_add<0x112>(ss);  // row_shr:2
      ss = dpp_add<0x114>(ss);  // row_shr:4
      ss = dpp_add<0x118>(ss);  // row_shr:8
      ss = dpp_add<0x142>(ss);  // row_bcast:15
      ss = dpp_add<0x143>(ss);  // row_bcast:31
      float tot = __int_as_float(__builtin_amdgcn_readlane(__float_as_int(ss), 63));
      float r = __builtin_amdgcn_rsqf(fmaf(tot, 9.765625e-4f, 1e-6f));

#pragma unroll
      for (int c = 0; c < 4; ++c) h4[c] = v4[c] * r;

      f32x4* hr = (f32x4*)(hout + ((size_t)(t + 1) * BATCH + b) * DIM);
      hr[2 * lane]       = h4[0];
      hr[2 * lane + 1]   = h4[1];
      hr[128 + 2 * lane] = h4[2];
      hr[129 + 2 * lane] = h4[3];
    }
  }
}

// ---------------------------------------------------------------------------
// out = h * silu(h) = h^2 * sigmoid(h), elementwise over hs (h rows 1..T)
__global__ void silu_out_kernel(const float* __restrict__ hsrc,
                                float* __restrict__ out, int n4) {
  int stride = gridDim.x * blockDim.x;
  for (int i = blockIdx.x * blockDim.x + threadIdx.x; i < n4; i += stride) {
    float4 v = reinterpret_cast<const float4*>(hsrc)[i];
    float4 o;
    o.x = v.x * v.x / (1.0f + __expf(-v.x));
    o.y = v.y * v.y / (1.0f + __expf(-v.y));
    o.z = v.z * v.z / (1.0f + __expf(-v.z));
    o.w = v.w * v.w / (1.0f + __expf(-v.w));
    reinterpret_cast<float4*>(out)[i] = o;
  }
}

// ---------------------------------------------------------------------------
extern "C" void kernel_launch(void* const* d_in, const int* in_sizes, int n_in,
                              void* d_out, int out_size, void* d_ws, size_t ws_size,
                              hipStream_t stream) {
  const float* x  = (const float*)d_in[0];  // [T,B,D]
  const float* h0 = (const float*)d_in[1];  // [B,D]
  const float* W  = (const float*)d_in[2];  // [D,D]
  const float* Wg = (const float*)d_in[3];  // [D,D]
  const float* bb = (const float*)d_in[4];  // [D]
  const float* bg = (const float*)d_in[5];  // [D]

  float* out  = (float*)d_out;                              // [T,B,D]
  float* hout = out + (size_t)T_STEPS * BATCH * DIM;        // [T+1,B,D]

  char* ws = (char*)d_ws;
  f16* xh  = (f16*)(ws);                                    // 64 MiB
  f16* wh  = (f16*)(ws + (size_t)67108864);                 // 2 MiB
  f16* wgh = (f16*)(ws + (size_t)69206016);                 // 2 MiB
  f16* P   = (f16*)(ws + (size_t)71303168);                 // 64 MiB

  cvt_kernel<<<16384, 256, 0, stream>>>(x,  xh,  4194304);
  cvt_kernel<<<512,   256, 0, stream>>>(W,  wh,  131072);
  cvt_kernel<<<512,   256, 0, stream>>>(Wg, wgh, 131072);

  dual_gemm<<<2048, 256, 0, stream>>>(xh, wh, wgh, bb, bg, P);

  scan_kernel<<<BATCH, 64, 0, stream>>>(P, h0, hout);

  silu_out_kernel<<<2048, 256, 0, stream>>>(hout + BATCH * DIM, out, 8388608);
}